// Round 4
// baseline (1862.079 us; speedup 1.0000x reference)
//
#include <hip/hip_runtime.h>

// NormEMAVectorQuantizer on MI355X (gfx950)
// N=8192 tokens, C=32, K=8192 codes, B=32, H*W=256.
// Strategy: bf16 MFMA (16x16x32, K=C=32) scores ALL token/code pairs on the
// matrix pipe; certified eps-filter (bf16 score err <= 2*2^-9 < 0.01 for unit
// rows) collects candidates; exact fp32 rescore + packed-u64 atomicMax
// reproduces numpy fp32 argmax with lowest-index tie-break.
//
// Outputs (float32, concatenated):
//   [0 .. 262144)        z_q_out [B,C,H,W]
//   [262144]             loss (scalar)
//   [262145 .. 270337)   token_ids [B,H,W] as float
//   [270337 .. 532481)   new_embedding [K,C]
//   [532481 .. 540673)   new_cluster_sizes [K]

#define NTOK   8192
#define NCODE  8192
#define CDIM   32
#define HW     256
#define DECAYF 0.99f
#define EPSF   0.01f

#define OUT_ZQ   0
#define OUT_LOSS 262144
#define OUT_IDS  262145
#define OUT_EMB  270337
#define OUT_CS   532481

// workspace byte offsets (R3 bug: packed is 64 KiB = 65536 B; bins must start
// at WS_PACK + 65536, not +64512 — the 1 KiB overlap corrupted bins[0..255])
#define WS_ZN    0u         // 8192*32 f32   = 1048576 B
#define WS_ZNBF  1048576u   // 8192*32 bf16  = 524288 B
#define WS_EBF   1572864u   // 8192*32 bf16  = 524288 B
#define WS_PACK  2097152u   // 8192 u64      = 65536 B   <- zeroed from here
#define WS_BINS  2162688u   // 8192 i32      = 32768 B
#define WS_ESUM  2195456u   // 8192*32 f32   = 1048576 B
#define WS_LOSS  3244032u   // 1 f32
#define WS_CNT   3244036u   // 1 u32
#define WS_ZEND  3244040u
#define WS_ZERO_BYTES (WS_ZEND - WS_PACK)
#define WS_LIST  3244040u   // candidate list, u32 packed (tok<<13|code)
#define LIST_MAX 524288u

#define CHUNK 512           // codes per k_select block
#define TILES (CHUNK / 16)

typedef __attribute__((ext_vector_type(8))) short bf16x8;
typedef __attribute__((ext_vector_type(4))) float f32x4;

__device__ inline unsigned short f2bf(float x) {
    unsigned u = __float_as_uint(x);
    return (unsigned short)((u + 0x7FFFu + ((u >> 16) & 1u)) >> 16);
}

// -------- Kernel A: token transpose+L2norm (+bf16) and emb bf16 convert --------
__global__ __launch_bounds__(256) void k_prep(const float* __restrict__ z,
                                              const float* __restrict__ emb,
                                              float* __restrict__ zn,
                                              unsigned short* __restrict__ znbf,
                                              unsigned short* __restrict__ ebf) {
    if (blockIdx.x < 32) {
        int n = blockIdx.x * 256 + threadIdx.x;   // token = b*256 + hw
        int b = n >> 8, hw = n & 255;
        const float* zp = z + (size_t)b * (CDIM * HW) + hw;
        float v[CDIM];
        float ss = 0.f;
#pragma unroll
        for (int c = 0; c < CDIM; ++c) {
            float t = zp[c * HW];
            v[c] = t;
            ss += t * t;
        }
        float d = fmaxf(sqrtf(ss), 1e-12f);
        float* o = zn + (size_t)n * CDIM;
        unsigned short* ob = znbf + (size_t)n * CDIM;
#pragma unroll
        for (int c = 0; c < CDIM; ++c) {
            float t = v[c] / d;
            o[c] = t;
            ob[c] = f2bf(t);
        }
    } else {
        int base = (blockIdx.x - 32) * 2048 + threadIdx.x * 8;
        const float4* s = (const float4*)(emb + base);
        float4 x = s[0], y = s[1];
        ushort4 u0 = {f2bf(x.x), f2bf(x.y), f2bf(x.z), f2bf(x.w)};
        ushort4 u1 = {f2bf(y.x), f2bf(y.y), f2bf(y.z), f2bf(y.w)};
        *(ushort4*)(ebf + base) = u0;
        *(ushort4*)(ebf + base + 4) = u1;
    }
}

// -------- Kernel B: MFMA bf16 score scan + certified candidate filter --------
// block = 4 waves, 256 tokens x 512 codes. Each wave: 64 tokens (4 A-frags).
// Phase A: per-token chunk max. Phase B: rescan, push (tok,code) with
// score >= max - eps. True fp32 argmax provably qualifies (2*2^-9 bound).
__global__ __launch_bounds__(256) void k_select(const unsigned short* __restrict__ znbf,
                                                const unsigned short* __restrict__ ebf,
                                                unsigned* __restrict__ list,
                                                unsigned* __restrict__ cnt) {
    __shared__ unsigned short lds[CHUNK * CDIM];   // 32 KiB
    int kbase = blockIdx.y * CHUNK;
    {   // stage code chunk: 512 rows x 64 B
        const float4* src = (const float4*)(ebf + (size_t)kbase * CDIM);
        float4* dst = (float4*)lds;
#pragma unroll
        for (int j = 0; j < 8; ++j)
            dst[threadIdx.x + j * 256] = src[threadIdx.x + j * 256];
    }
    __syncthreads();

    int wave = threadIdx.x >> 6;
    int lane = threadIdx.x & 63;
    int col = lane & 15, quad = lane >> 4;
    int wtok = blockIdx.x * 256 + wave * 64;

    bf16x8 a[4];                                   // A-frags: 64 tokens
#pragma unroll
    for (int f = 0; f < 4; ++f)
        a[f] = *(const bf16x8*)(znbf + ((size_t)(wtok + f * 16 + col)) * CDIM + quad * 8);

    const bf16x8* bl = (const bf16x8*)lds;         // 16B units
    const f32x4 zero4 = {0.f, 0.f, 0.f, 0.f};

    float m[4][4];
#pragma unroll
    for (int f = 0; f < 4; ++f)
#pragma unroll
        for (int r = 0; r < 4; ++r) m[f][r] = -1e30f;

    for (int t = 0; t < TILES; ++t) {              // phase A: running max
        bf16x8 b = bl[(t * 16 + col) * 4 + quad];
#pragma unroll
        for (int f = 0; f < 4; ++f) {
            f32x4 d = __builtin_amdgcn_mfma_f32_16x16x32_bf16(a[f], b, zero4, 0, 0, 0);
#pragma unroll
            for (int r = 0; r < 4; ++r) m[f][r] = fmaxf(m[f][r], d[r]);
        }
    }
    // cross-column max (16 lanes sharing `quad`), then subtract eps
#pragma unroll
    for (int f = 0; f < 4; ++f)
#pragma unroll
        for (int r = 0; r < 4; ++r) {
            float v = m[f][r];
#pragma unroll
            for (int s = 1; s < 16; s <<= 1) v = fmaxf(v, __shfl_xor(v, s));
            m[f][r] = v - EPSF;
        }

    for (int t = 0; t < TILES; ++t) {              // phase B: push qualifiers
        bf16x8 b = bl[(t * 16 + col) * 4 + quad];
#pragma unroll
        for (int f = 0; f < 4; ++f) {
            f32x4 d = __builtin_amdgcn_mfma_f32_16x16x32_bf16(a[f], b, zero4, 0, 0, 0);
#pragma unroll
            for (int r = 0; r < 4; ++r) {
                if (d[r] >= m[f][r]) {
                    unsigned tok = wtok + f * 16 + quad * 4 + r;
                    unsigned code = kbase + t * 16 + col;
                    unsigned idx = atomicAdd(cnt, 1u);
                    if (idx < LIST_MAX) list[idx] = (tok << 13) | code;
                }
            }
        }
    }
}

// -------- Kernel C: exact fp32 rescore of candidates, argmax via atomicMax --------
__global__ __launch_bounds__(256) void k_rescore(const unsigned* __restrict__ list,
                                                 const unsigned* __restrict__ cnt,
                                                 const float* __restrict__ zn,
                                                 const float* __restrict__ emb,
                                                 unsigned long long* __restrict__ packed) {
    unsigned n = cnt[0];
    if (n > LIST_MAX) n = LIST_MAX;
    for (unsigned i = blockIdx.x * 256 + threadIdx.x; i < n; i += gridDim.x * 256) {
        unsigned p = list[i];
        unsigned tok = (p >> 13) & 8191u, code = p & 8191u;  // masked: never OOB
        const float* zp = zn + (size_t)tok * CDIM;
        const float* ep = emb + (size_t)code * CDIM;
        float a0 = 0.f, a1 = 0.f, a2 = 0.f, a3 = 0.f;
#pragma unroll
        for (int j = 0; j < 8; ++j) {
            a0 = __builtin_fmaf(zp[4 * j + 0], ep[4 * j + 0], a0);
            a1 = __builtin_fmaf(zp[4 * j + 1], ep[4 * j + 1], a1);
            a2 = __builtin_fmaf(zp[4 * j + 2], ep[4 * j + 2], a2);
            a3 = __builtin_fmaf(zp[4 * j + 3], ep[4 * j + 3], a3);
        }
        float s = (a0 + a1) + (a2 + a3);
        unsigned u = __float_as_uint(s);
        u = (u & 0x80000000u) ? ~u : (u | 0x80000000u);
        atomicMax(packed + tok,
                  ((unsigned long long)u << 13) | (unsigned long long)(8191 - code));
    }
}

// -------- Kernel D: unpack ids, scatter, z_q gather+transpose, loss --------
// block = (b, c) pair: 1024 blocks x 256 hw-threads.
__global__ __launch_bounds__(256) void k_scatter_out(const unsigned long long* __restrict__ packed,
                                                     const float* __restrict__ zn,
                                                     const float* __restrict__ emb,
                                                     int* __restrict__ bins,
                                                     float* __restrict__ esum,
                                                     float* __restrict__ out,
                                                     float* __restrict__ loss_acc) {
    int b = blockIdx.x >> 5, c = blockIdx.x & 31;
    int hw = threadIdx.x;
    int n = b * 256 + hw;
    unsigned long long key = packed[n];
    int id = 8191 - (int)(key & 8191ull);
    float ev = emb[(size_t)id * CDIM + c];
    float zv = zn[(size_t)n * CDIM + c];
    out[OUT_ZQ + ((size_t)b * CDIM + c) * HW + hw] = ev;     // coalesced
    atomicAdd(esum + (size_t)id * CDIM + c, zv);
    float dd = ev - zv;
    float s = dd * dd;
#pragma unroll
    for (int off = 32; off > 0; off >>= 1) s += __shfl_down(s, off);
    if ((hw & 63) == 0) atomicAdd(loss_acc, s);
    if (c == 0) {
        atomicAdd(bins + id, 1);
        out[OUT_IDS + n] = (float)id;
    }
}

// -------- Kernel E: EMA update + renormalize (thread per (k,c), wave shuffles) ----
__global__ __launch_bounds__(256) void k_update(const float* __restrict__ emb,
                                                const float* __restrict__ cs,
                                                const int* __restrict__ bins,
                                                const float* __restrict__ esum,
                                                const float* __restrict__ loss_acc,
                                                float* __restrict__ out) {
    int idx = blockIdx.x * 256 + threadIdx.x;
    int k = idx >> 5, c = idx & 31;
    int bi = bins[k];
    float bf = (float)bi;
    bool zero = (bi == 0);
    float bc = zero ? 1.0f : bf;
    float t = esum[idx] / bc;
    float ss = t * t;
#pragma unroll
    for (int s = 1; s < 32; s <<= 1) ss += __shfl_xor(ss, s);
    float d = fmaxf(sqrtf(ss), 1e-12f);
    float ew = emb[idx];
    float en = zero ? ew : (t / d);
    float w = ew * DECAYF + (1.0f - DECAYF) * en;
    float ss2 = w * w;
#pragma unroll
    for (int s = 1; s < 32; s <<= 1) ss2 += __shfl_xor(ss2, s);
    float d2 = fmaxf(sqrtf(ss2), 1e-12f);
    out[OUT_EMB + idx] = w / d2;
    if (c == 0) out[OUT_CS + k] = cs[k] * DECAYF + (1.0f - DECAYF) * bf;
    if (idx == 0) out[OUT_LOSS] = loss_acc[0] * (1.0f / 262144.0f);
}

extern "C" void kernel_launch(void* const* d_in, const int* in_sizes, int n_in,
                              void* d_out, int out_size, void* d_ws, size_t ws_size,
                              hipStream_t stream) {
    const float* z   = (const float*)d_in[0];   // [32,32,16,16]
    const float* emb = (const float*)d_in[1];   // [8192,32]
    const float* cs  = (const float*)d_in[2];   // [8192]
    float* out = (float*)d_out;
    char* ws = (char*)d_ws;

    float* zn                  = (float*)(ws + WS_ZN);
    unsigned short* znbf       = (unsigned short*)(ws + WS_ZNBF);
    unsigned short* ebf        = (unsigned short*)(ws + WS_EBF);
    unsigned long long* packed = (unsigned long long*)(ws + WS_PACK);
    int* bins                  = (int*)(ws + WS_BINS);
    float* esum                = (float*)(ws + WS_ESUM);
    float* loss_acc            = (float*)(ws + WS_LOSS);
    unsigned* cnt              = (unsigned*)(ws + WS_CNT);
    unsigned* list             = (unsigned*)(ws + WS_LIST);

    hipMemsetAsync(ws + WS_PACK, 0, WS_ZERO_BYTES, stream);

    k_prep<<<dim3(160), 256, 0, stream>>>(z, emb, zn, znbf, ebf);
    k_select<<<dim3(NTOK / 256, NCODE / CHUNK), 256, 0, stream>>>(znbf, ebf, list, cnt);
    k_rescore<<<dim3(512), 256, 0, stream>>>(list, cnt, zn, emb, packed);
    k_scatter_out<<<dim3(1024), 256, 0, stream>>>(packed, zn, emb, bins, esum, out, loss_acc);
    k_update<<<dim3(1024), 256, 0, stream>>>(emb, cs, bins, esum, loss_acc, out);
}

// Round 5
// 228.580 us; speedup vs baseline: 8.1463x; 8.1463x over previous
//
#include <hip/hip_runtime.h>

// NormEMAVectorQuantizer on MI355X (gfx950)
// N=8192 tokens, C=32, K=8192 codes, B=32, H*W=256.
// bf16 MFMA (16x16x32) scores all pairs; certified eps-filter (bf16 err
// <= 2*2^-9 < 0.01 for unit rows) qualifies candidates; qualifying lanes
// rescore EXACTLY in fp32 inline and atomicMax a packed (score,code) key
// per token (8192 addresses -> no contention). R4's single-address
// atomicAdd counter (145K serialized fetch-adds ~= 1.7 ms) is eliminated.
//
// Outputs (float32, concatenated):
//   [0 .. 262144)        z_q_out [B,C,H,W]
//   [262144]             loss (scalar)
//   [262145 .. 270337)   token_ids [B,H,W] as float
//   [270337 .. 532481)   new_embedding [K,C]
//   [532481 .. 540673)   new_cluster_sizes [K]

#define NTOK   8192
#define NCODE  8192
#define CDIM   32
#define HW     256
#define DECAYF 0.99f
#define EPSF   0.01f

#define OUT_ZQ   0
#define OUT_LOSS 262144
#define OUT_IDS  262145
#define OUT_EMB  270337
#define OUT_CS   532481

// workspace byte offsets
#define WS_ZN    0u         // 8192*32 f32   = 1048576 B
#define WS_ZNBF  1048576u   // 8192*32 bf16  = 524288 B
#define WS_EBF   1572864u   // 8192*32 bf16  = 524288 B
#define WS_PACK  2097152u   // 8192 u64      = 65536 B   <- zeroed from here
#define WS_BINS  2162688u   // 8192 i32      = 32768 B
#define WS_ESUM  2195456u   // 8192*32 f32   = 1048576 B
#define WS_LOSS  3244032u   // 1 f32
#define WS_ZEND  3244036u
#define WS_ZERO_BYTES (WS_ZEND - WS_PACK)

#define CHUNK 512           // codes per k_select block
#define TILES (CHUNK / 16)

typedef __attribute__((ext_vector_type(8))) short bf16x8;
typedef __attribute__((ext_vector_type(4))) float f32x4;

__device__ inline unsigned short f2bf(float x) {
    unsigned u = __float_as_uint(x);
    return (unsigned short)((u + 0x7FFFu + ((u >> 16) & 1u)) >> 16);
}

// -------- Kernel A: token transpose+L2norm (+bf16) and emb bf16 convert --------
__global__ __launch_bounds__(256) void k_prep(const float* __restrict__ z,
                                              const float* __restrict__ emb,
                                              float* __restrict__ zn,
                                              unsigned short* __restrict__ znbf,
                                              unsigned short* __restrict__ ebf) {
    if (blockIdx.x < 32) {
        int n = blockIdx.x * 256 + threadIdx.x;   // token = b*256 + hw
        int b = n >> 8, hw = n & 255;
        const float* zp = z + (size_t)b * (CDIM * HW) + hw;
        float v[CDIM];
        float ss = 0.f;
#pragma unroll
        for (int c = 0; c < CDIM; ++c) {
            float t = zp[c * HW];
            v[c] = t;
            ss += t * t;
        }
        float d = fmaxf(sqrtf(ss), 1e-12f);
        float* o = zn + (size_t)n * CDIM;
        unsigned short* ob = znbf + (size_t)n * CDIM;
#pragma unroll
        for (int c = 0; c < CDIM; ++c) {
            float t = v[c] / d;
            o[c] = t;
            ob[c] = f2bf(t);
        }
    } else {
        int base = (blockIdx.x - 32) * 2048 + threadIdx.x * 8;
        const float4* s = (const float4*)(emb + base);
        float4 x = s[0], y = s[1];
        ushort4 u0 = {f2bf(x.x), f2bf(x.y), f2bf(x.z), f2bf(x.w)};
        ushort4 u1 = {f2bf(y.x), f2bf(y.y), f2bf(y.z), f2bf(y.w)};
        *(ushort4*)(ebf + base) = u0;
        *(ushort4*)(ebf + base + 4) = u1;
    }
}

// -------- Kernel B: MFMA scan + certified filter + INLINE exact fp32 rescore ----
// block = 4 waves, 256 tokens x 512 codes. Wave: 64 tokens (4 A-frags).
// Phase A: per-token chunk max. Phase B: lanes whose bf16 score >= max-eps
// compute the exact fp32 dot (same chain order as the R1/R2-verified kernel)
// and atomicMax packed[tok] with (monotonic_u32(score)<<13 | (8191-code)).
__global__ __launch_bounds__(256) void k_select(const unsigned short* __restrict__ znbf,
                                                const unsigned short* __restrict__ ebf,
                                                const float* __restrict__ zn,
                                                const float* __restrict__ emb,
                                                unsigned long long* __restrict__ packed) {
    __shared__ unsigned short lds[CHUNK * CDIM];   // 32 KiB
    int kbase = blockIdx.y * CHUNK;
    {   // stage code chunk: 512 rows x 64 B
        const float4* src = (const float4*)(ebf + (size_t)kbase * CDIM);
        float4* dst = (float4*)lds;
#pragma unroll
        for (int j = 0; j < 8; ++j)
            dst[threadIdx.x + j * 256] = src[threadIdx.x + j * 256];
    }
    __syncthreads();

    int wave = threadIdx.x >> 6;
    int lane = threadIdx.x & 63;
    int col = lane & 15, quad = lane >> 4;
    int wtok = blockIdx.x * 256 + wave * 64;

    bf16x8 a[4];                                   // A-frags: 64 tokens
#pragma unroll
    for (int f = 0; f < 4; ++f)
        a[f] = *(const bf16x8*)(znbf + ((size_t)(wtok + f * 16 + col)) * CDIM + quad * 8);

    const bf16x8* bl = (const bf16x8*)lds;         // 16B units
    const f32x4 zero4 = {0.f, 0.f, 0.f, 0.f};

    float m[4][4];
#pragma unroll
    for (int f = 0; f < 4; ++f)
#pragma unroll
        for (int r = 0; r < 4; ++r) m[f][r] = -1e30f;

    for (int t = 0; t < TILES; ++t) {              // phase A: running max
        bf16x8 b = bl[(t * 16 + col) * 4 + quad];
#pragma unroll
        for (int f = 0; f < 4; ++f) {
            f32x4 d = __builtin_amdgcn_mfma_f32_16x16x32_bf16(a[f], b, zero4, 0, 0, 0);
#pragma unroll
            for (int r = 0; r < 4; ++r) m[f][r] = fmaxf(m[f][r], d[r]);
        }
    }
    // cross-column max (16 lanes sharing `quad`), then subtract eps
#pragma unroll
    for (int f = 0; f < 4; ++f)
#pragma unroll
        for (int r = 0; r < 4; ++r) {
            float v = m[f][r];
#pragma unroll
            for (int s = 1; s < 16; s <<= 1) v = fmaxf(v, __shfl_xor(v, s));
            m[f][r] = v - EPSF;
        }

    for (int t = 0; t < TILES; ++t) {              // phase B: qualify -> rescore
        bf16x8 b = bl[(t * 16 + col) * 4 + quad];
#pragma unroll
        for (int f = 0; f < 4; ++f) {
            f32x4 d = __builtin_amdgcn_mfma_f32_16x16x32_bf16(a[f], b, zero4, 0, 0, 0);
#pragma unroll
            for (int r = 0; r < 4; ++r) {
                if (d[r] >= m[f][r]) {
                    int tok = wtok + f * 16 + quad * 4 + r;
                    int code = kbase + t * 16 + col;
                    const float* zp = zn + (size_t)tok * CDIM;
                    const float* ep = emb + (size_t)code * CDIM;
                    float a0 = 0.f, a1 = 0.f, a2 = 0.f, a3 = 0.f;
#pragma unroll
                    for (int j = 0; j < 8; ++j) {
                        a0 = __builtin_fmaf(zp[4 * j + 0], ep[4 * j + 0], a0);
                        a1 = __builtin_fmaf(zp[4 * j + 1], ep[4 * j + 1], a1);
                        a2 = __builtin_fmaf(zp[4 * j + 2], ep[4 * j + 2], a2);
                        a3 = __builtin_fmaf(zp[4 * j + 3], ep[4 * j + 3], a3);
                    }
                    float s = (a0 + a1) + (a2 + a3);
                    unsigned u = __float_as_uint(s);
                    u = (u & 0x80000000u) ? ~u : (u | 0x80000000u);
                    atomicMax(packed + tok, ((unsigned long long)u << 13) |
                                            (unsigned long long)(8191 - code));
                }
            }
        }
    }
}

// -------- Kernel D: unpack ids, scatter, z_q gather+transpose, loss --------
// block = (b, c) pair: 1024 blocks x 256 hw-threads.
__global__ __launch_bounds__(256) void k_scatter_out(const unsigned long long* __restrict__ packed,
                                                     const float* __restrict__ zn,
                                                     const float* __restrict__ emb,
                                                     int* __restrict__ bins,
                                                     float* __restrict__ esum,
                                                     float* __restrict__ out,
                                                     float* __restrict__ loss_acc) {
    int b = blockIdx.x >> 5, c = blockIdx.x & 31;
    int hw = threadIdx.x;
    int n = b * 256 + hw;
    unsigned long long key = packed[n];
    int id = 8191 - (int)(key & 8191ull);
    float ev = emb[(size_t)id * CDIM + c];
    float zv = zn[(size_t)n * CDIM + c];
    out[OUT_ZQ + ((size_t)b * CDIM + c) * HW + hw] = ev;     // coalesced
    atomicAdd(esum + (size_t)id * CDIM + c, zv);
    float dd = ev - zv;
    float s = dd * dd;
#pragma unroll
    for (int off = 32; off > 0; off >>= 1) s += __shfl_down(s, off);
    if ((hw & 63) == 0) atomicAdd(loss_acc, s);
    if (c == 0) {
        atomicAdd(bins + id, 1);
        out[OUT_IDS + n] = (float)id;
    }
}

// -------- Kernel E: EMA update + renormalize (thread per (k,c), wave shuffles) ----
__global__ __launch_bounds__(256) void k_update(const float* __restrict__ emb,
                                                const float* __restrict__ cs,
                                                const int* __restrict__ bins,
                                                const float* __restrict__ esum,
                                                const float* __restrict__ loss_acc,
                                                float* __restrict__ out) {
    int idx = blockIdx.x * 256 + threadIdx.x;
    int k = idx >> 5, c = idx & 31;
    int bi = bins[k];
    float bf = (float)bi;
    bool zero = (bi == 0);
    float bc = zero ? 1.0f : bf;
    float t = esum[idx] / bc;
    float ss = t * t;
#pragma unroll
    for (int s = 1; s < 32; s <<= 1) ss += __shfl_xor(ss, s);
    float d = fmaxf(sqrtf(ss), 1e-12f);
    float ew = emb[idx];
    float en = zero ? ew : (t / d);
    float w = ew * DECAYF + (1.0f - DECAYF) * en;
    float ss2 = w * w;
#pragma unroll
    for (int s = 1; s < 32; s <<= 1) ss2 += __shfl_xor(ss2, s);
    float d2 = fmaxf(sqrtf(ss2), 1e-12f);
    out[OUT_EMB + idx] = w / d2;
    if (c == 0) out[OUT_CS + k] = cs[k] * DECAYF + (1.0f - DECAYF) * bf;
    if (idx == 0) out[OUT_LOSS] = loss_acc[0] * (1.0f / 262144.0f);
}

extern "C" void kernel_launch(void* const* d_in, const int* in_sizes, int n_in,
                              void* d_out, int out_size, void* d_ws, size_t ws_size,
                              hipStream_t stream) {
    const float* z   = (const float*)d_in[0];   // [32,32,16,16]
    const float* emb = (const float*)d_in[1];   // [8192,32]
    const float* cs  = (const float*)d_in[2];   // [8192]
    float* out = (float*)d_out;
    char* ws = (char*)d_ws;

    float* zn                  = (float*)(ws + WS_ZN);
    unsigned short* znbf       = (unsigned short*)(ws + WS_ZNBF);
    unsigned short* ebf        = (unsigned short*)(ws + WS_EBF);
    unsigned long long* packed = (unsigned long long*)(ws + WS_PACK);
    int* bins                  = (int*)(ws + WS_BINS);
    float* esum                = (float*)(ws + WS_ESUM);
    float* loss_acc            = (float*)(ws + WS_LOSS);

    hipMemsetAsync(ws + WS_PACK, 0, WS_ZERO_BYTES, stream);

    k_prep<<<dim3(160), 256, 0, stream>>>(z, emb, zn, znbf, ebf);
    k_select<<<dim3(NTOK / 256, NCODE / CHUNK), 256, 0, stream>>>(znbf, ebf, zn, emb, packed);
    k_scatter_out<<<dim3(1024), 256, 0, stream>>>(packed, zn, emb, bins, esum, out, loss_acc);
    k_update<<<dim3(1024), 256, 0, stream>>>(emb, cs, bins, esum, loss_acc, out);
}

// Round 6
// 172.476 us; speedup vs baseline: 10.7962x; 1.3253x over previous
//
#include <hip/hip_runtime.h>

// NormEMAVectorQuantizer on MI355X (gfx950)
// N=8192 tokens, C=32, K=8192 codes, B=32, H*W=256.
// R6: two-phase certified argmax. k_max: bf16-MFMA scan -> per-token GLOBAL
// bf16 max (u32 monotonic key, atomicMax over 8192 addrs). k_pick: rescan,
// candidates = scores >= globalmax - eps (~1.05/token, vs 145K chunk-local
// candidates in R5); qualifying lanes rescore exactly in fp32 and atomicMax
// a packed (score,code) u64 per token. Certificate: bf16 score err <= 2*2^-9
// = 0.0078 < eps for unit-norm rows, so the fp32 argmax always qualifies.
//
// Outputs (float32, concatenated):
//   [0 .. 262144)        z_q_out [B,C,H,W]
//   [262144]             loss (scalar)
//   [262145 .. 270337)   token_ids [B,H,W] as float
//   [270337 .. 532481)   new_embedding [K,C]
//   [532481 .. 540673)   new_cluster_sizes [K]

#define NTOK   8192
#define NCODE  8192
#define CDIM   32
#define HW     256
#define DECAYF 0.99f
#define EPSF   0.01f

#define OUT_ZQ   0
#define OUT_LOSS 262144
#define OUT_IDS  262145
#define OUT_EMB  270337
#define OUT_CS   532481

// workspace byte offsets
#define WS_ZN    0u         // 8192*32 f32 = 1048576 B
#define WS_PACK  1048576u   // 8192 u64    = 65536 B   <- zeroed from here
#define WS_MAXS  1114112u   // 8192 u32    = 32768 B
#define WS_BINS  1146880u   // 8192 i32    = 32768 B
#define WS_ESUM  1179648u   // 8192*32 f32 = 1048576 B
#define WS_LOSS  2228224u   // 1 f32
#define WS_ZEND  2228228u
#define WS_ZERO_BYTES (WS_ZEND - WS_PACK)

#define CHUNK 256           // codes per block in k_max/k_pick
#define TILES (CHUNK / 16)  // 16

typedef __attribute__((ext_vector_type(8))) short bf16x8;
typedef __attribute__((ext_vector_type(4))) float f32x4;

__device__ inline unsigned short f2bf(float x) {
    unsigned u = __float_as_uint(x);
    return (unsigned short)((u + 0x7FFFu + ((u >> 16) & 1u)) >> 16);
}
// monotonic f32 -> u32 (order-preserving); inverse for thresholds
__device__ inline unsigned fmap(float s) {
    unsigned u = __float_as_uint(s);
    return (u & 0x80000000u) ? ~u : (u | 0x80000000u);
}
__device__ inline float funmap(unsigned u) {
    unsigned o = (u & 0x80000000u) ? (u & 0x7FFFFFFFu) : ~u;
    return __uint_as_float(o);
}

// -------- Kernel A: channel-last transpose + L2 normalize (fp32 only) --------
__global__ __launch_bounds__(256) void k_prep(const float* __restrict__ z,
                                              float* __restrict__ zn) {
    int n = blockIdx.x * 256 + threadIdx.x;       // token = b*256 + hw
    int b = n >> 8, hw = n & 255;
    const float* zp = z + (size_t)b * (CDIM * HW) + hw;
    float v[CDIM];
    float ss = 0.f;
#pragma unroll
    for (int c = 0; c < CDIM; ++c) {
        float t = zp[c * HW];
        v[c] = t;
        ss += t * t;
    }
    float d = fmaxf(sqrtf(ss), 1e-12f);
    float* o = zn + (size_t)n * CDIM;
#pragma unroll
    for (int c = 0; c < CDIM; ++c) o[c] = v[c] / d;
}

// helper: stage one emb chunk (CHUNK x 32 fp32) as bf16 into LDS, row-major
__device__ inline void stage_emb_bf16(const float* __restrict__ emb, int kbase,
                                      unsigned short* lbs) {
    const float4* src = (const float4*)(emb + (size_t)kbase * CDIM);
    ushort4* dst = (ushort4*)lbs;
#pragma unroll
    for (int i = 0; i < 8; ++i) {
        int j = threadIdx.x + i * 256;            // float4 index within chunk
        float4 v = src[j];
        ushort4 h;
        h.x = f2bf(v.x); h.y = f2bf(v.y); h.z = f2bf(v.z); h.w = f2bf(v.w);
        dst[j] = h;
    }
}

// helper: load 4 A-frags (64 tokens) from fp32 zn, converting to bf16
__device__ inline void load_afrags(const float* __restrict__ zn, int wtok,
                                   int col, int quad, bf16x8* a) {
#pragma unroll
    for (int f = 0; f < 4; ++f) {
        const float4* zp =
            (const float4*)(zn + (size_t)(wtok + f * 16 + col) * CDIM + quad * 8);
        float4 x = zp[0], y = zp[1];
        bf16x8 v;
        v[0] = (short)f2bf(x.x); v[1] = (short)f2bf(x.y);
        v[2] = (short)f2bf(x.z); v[3] = (short)f2bf(x.w);
        v[4] = (short)f2bf(y.x); v[5] = (short)f2bf(y.y);
        v[6] = (short)f2bf(y.z); v[7] = (short)f2bf(y.w);
        a[f] = v;
    }
}

// -------- Kernel B1: MFMA scan -> per-token global bf16 max --------
// grid (32 token-blocks, 32 code-chunks), 256 thr = 4 waves.
__global__ __launch_bounds__(256) void k_max(const float* __restrict__ zn,
                                             const float* __restrict__ emb,
                                             unsigned* __restrict__ maxs) {
    __shared__ unsigned short lbs[CHUNK * CDIM];  // 16 KiB
    int kbase = blockIdx.y * CHUNK;
    stage_emb_bf16(emb, kbase, lbs);
    __syncthreads();

    int wave = threadIdx.x >> 6, lane = threadIdx.x & 63;
    int col = lane & 15, quad = lane >> 4;
    int wtok = blockIdx.x * 256 + wave * 64;

    bf16x8 a[4];
    load_afrags(zn, wtok, col, quad, a);

    const bf16x8* bl = (const bf16x8*)lbs;
    const f32x4 zero4 = {0.f, 0.f, 0.f, 0.f};
    float m[4][4];
#pragma unroll
    for (int f = 0; f < 4; ++f)
#pragma unroll
        for (int r = 0; r < 4; ++r) m[f][r] = -1e30f;

    for (int t = 0; t < TILES; ++t) {
        bf16x8 b = bl[(t * 16 + col) * 4 + quad];
#pragma unroll
        for (int f = 0; f < 4; ++f) {
            f32x4 d = __builtin_amdgcn_mfma_f32_16x16x32_bf16(a[f], b, zero4, 0, 0, 0);
#pragma unroll
            for (int r = 0; r < 4; ++r) m[f][r] = fmaxf(m[f][r], d[r]);
        }
    }
    // reduce over the 16 code-columns (lanes sharing quad = low-4 lane bits)
#pragma unroll
    for (int f = 0; f < 4; ++f)
#pragma unroll
        for (int r = 0; r < 4; ++r) {
            float v = m[f][r];
#pragma unroll
            for (int s = 1; s < 16; s <<= 1) v = fmaxf(v, __shfl_xor(v, s));
            if (col == 0)
                atomicMax(maxs + (wtok + f * 16 + quad * 4 + r), fmap(v));
        }
}

// -------- Kernel B2: MFMA rescan, candidates >= globalmax-eps -> exact rescore ---
__global__ __launch_bounds__(256) void k_pick(const float* __restrict__ zn,
                                              const float* __restrict__ emb,
                                              const unsigned* __restrict__ maxs,
                                              unsigned long long* __restrict__ packed) {
    __shared__ unsigned short lbs[CHUNK * CDIM];  // 16 KiB
    __shared__ float lthr[256];
    int kbase = blockIdx.y * CHUNK;
    stage_emb_bf16(emb, kbase, lbs);
    lthr[threadIdx.x] = funmap(maxs[blockIdx.x * 256 + threadIdx.x]) - EPSF;
    __syncthreads();

    int wave = threadIdx.x >> 6, lane = threadIdx.x & 63;
    int col = lane & 15, quad = lane >> 4;
    int wtok = blockIdx.x * 256 + wave * 64;

    bf16x8 a[4];
    load_afrags(zn, wtok, col, quad, a);

    float thr[4][4];
#pragma unroll
    for (int f = 0; f < 4; ++f)
#pragma unroll
        for (int r = 0; r < 4; ++r)
            thr[f][r] = lthr[wave * 64 + f * 16 + quad * 4 + r];  // broadcast read

    const bf16x8* bl = (const bf16x8*)lbs;
    const f32x4 zero4 = {0.f, 0.f, 0.f, 0.f};

    for (int t = 0; t < TILES; ++t) {
        bf16x8 b = bl[(t * 16 + col) * 4 + quad];
#pragma unroll
        for (int f = 0; f < 4; ++f) {
            f32x4 d = __builtin_amdgcn_mfma_f32_16x16x32_bf16(a[f], b, zero4, 0, 0, 0);
#pragma unroll
            for (int r = 0; r < 4; ++r) {
                if (d[r] >= thr[f][r]) {          // rare: ~1.05 per token total
                    int tok = wtok + f * 16 + quad * 4 + r;
                    int code = kbase + t * 16 + col;
                    const float* zp = zn + (size_t)tok * CDIM;
                    const float* ep = emb + (size_t)code * CDIM;
                    float a0 = 0.f, a1 = 0.f, a2 = 0.f, a3 = 0.f;
#pragma unroll
                    for (int j = 0; j < 8; ++j) {
                        a0 = __builtin_fmaf(zp[4 * j + 0], ep[4 * j + 0], a0);
                        a1 = __builtin_fmaf(zp[4 * j + 1], ep[4 * j + 1], a1);
                        a2 = __builtin_fmaf(zp[4 * j + 2], ep[4 * j + 2], a2);
                        a3 = __builtin_fmaf(zp[4 * j + 3], ep[4 * j + 3], a3);
                    }
                    float s = (a0 + a1) + (a2 + a3);
                    atomicMax(packed + tok, ((unsigned long long)fmap(s) << 13) |
                                            (unsigned long long)(8191 - code));
                }
            }
        }
    }
}

// -------- Kernel D: unpack ids, scatter, z_q gather+transpose, loss --------
// block = (b, c) pair: 1024 blocks x 256 hw-threads.
__global__ __launch_bounds__(256) void k_scatter_out(const unsigned long long* __restrict__ packed,
                                                     const float* __restrict__ zn,
                                                     const float* __restrict__ emb,
                                                     int* __restrict__ bins,
                                                     float* __restrict__ esum,
                                                     float* __restrict__ out,
                                                     float* __restrict__ loss_acc) {
    int b = blockIdx.x >> 5, c = blockIdx.x & 31;
    int hw = threadIdx.x;
    int n = b * 256 + hw;
    unsigned long long key = packed[n];
    int id = 8191 - (int)(key & 8191ull);
    float ev = emb[(size_t)id * CDIM + c];
    float zv = zn[(size_t)n * CDIM + c];
    out[OUT_ZQ + ((size_t)b * CDIM + c) * HW + hw] = ev;     // coalesced
    atomicAdd(esum + (size_t)id * CDIM + c, zv);
    float dd = ev - zv;
    float s = dd * dd;
#pragma unroll
    for (int off = 32; off > 0; off >>= 1) s += __shfl_down(s, off);
    if ((hw & 63) == 0) atomicAdd(loss_acc, s);
    if (c == 0) {
        atomicAdd(bins + id, 1);
        out[OUT_IDS + n] = (float)id;
    }
}

// -------- Kernel E: EMA update + renormalize (thread per (k,c), wave shuffles) ----
__global__ __launch_bounds__(256) void k_update(const float* __restrict__ emb,
                                                const float* __restrict__ cs,
                                                const int* __restrict__ bins,
                                                const float* __restrict__ esum,
                                                const float* __restrict__ loss_acc,
                                                float* __restrict__ out) {
    int idx = blockIdx.x * 256 + threadIdx.x;
    int k = idx >> 5, c = idx & 31;
    int bi = bins[k];
    float bf = (float)bi;
    bool zero = (bi == 0);
    float bc = zero ? 1.0f : bf;
    float t = esum[idx] / bc;
    float ss = t * t;
#pragma unroll
    for (int s = 1; s < 32; s <<= 1) ss += __shfl_xor(ss, s);
    float d = fmaxf(sqrtf(ss), 1e-12f);
    float ew = emb[idx];
    float en = zero ? ew : (t / d);
    float w = ew * DECAYF + (1.0f - DECAYF) * en;
    float ss2 = w * w;
#pragma unroll
    for (int s = 1; s < 32; s <<= 1) ss2 += __shfl_xor(ss2, s);
    float d2 = fmaxf(sqrtf(ss2), 1e-12f);
    out[OUT_EMB + idx] = w / d2;
    if (c == 0) out[OUT_CS + k] = cs[k] * DECAYF + (1.0f - DECAYF) * bf;
    if (idx == 0) out[OUT_LOSS] = loss_acc[0] * (1.0f / 262144.0f);
}

extern "C" void kernel_launch(void* const* d_in, const int* in_sizes, int n_in,
                              void* d_out, int out_size, void* d_ws, size_t ws_size,
                              hipStream_t stream) {
    const float* z   = (const float*)d_in[0];   // [32,32,16,16]
    const float* emb = (const float*)d_in[1];   // [8192,32]
    const float* cs  = (const float*)d_in[2];   // [8192]
    float* out = (float*)d_out;
    char* ws = (char*)d_ws;

    float* zn                  = (float*)(ws + WS_ZN);
    unsigned long long* packed = (unsigned long long*)(ws + WS_PACK);
    unsigned* maxs             = (unsigned*)(ws + WS_MAXS);
    int* bins                  = (int*)(ws + WS_BINS);
    float* esum                = (float*)(ws + WS_ESUM);
    float* loss_acc            = (float*)(ws + WS_LOSS);

    hipMemsetAsync(ws + WS_PACK, 0, WS_ZERO_BYTES, stream);

    k_prep<<<dim3(NTOK / 256), 256, 0, stream>>>(z, zn);
    k_max<<<dim3(NTOK / 256, NCODE / CHUNK), 256, 0, stream>>>(zn, emb, maxs);
    k_pick<<<dim3(NTOK / 256, NCODE / CHUNK), 256, 0, stream>>>(zn, emb, maxs, packed);
    k_scatter_out<<<dim3(1024), 256, 0, stream>>>(packed, zn, emb, bins, esum, out, loss_acc);
    k_update<<<dim3(1024), 256, 0, stream>>>(emb, cs, bins, esum, loss_acc, out);
}

// Round 7
// 146.433 us; speedup vs baseline: 12.7163x; 1.1779x over previous
//
#include <hip/hip_runtime.h>

// NormEMAVectorQuantizer on MI355X (gfx950)
// N=8192 tokens, C=32, K=8192 codes, B=32, H*W=256.
// R7: zero scattered-atomic design.
//  - k_max: bf16-MFMA scan -> per-(chunk,token) partial max, DIRECT stores
//    (R6's 262K atomicMax storm removed).
//  - k_pick: reduce 32 partials/token (coalesced), candidates >= gmax-eps
//    (certified: bf16 dot err <= 2*2^-9 = 0.0078 < 0.01 for unit rows),
//    inline exact fp32 rescore -> ~9K atomicMax on packed[tok].
//  - esum via counting sort: pos[n]=atomicAdd(bins+id,1) (8K atomics only),
//    single-block scan+place, k_update gathers each code's segment directly
//    (R6's 262K scattered fp32 atomicAdd storm removed).
//
// Outputs (float32, concatenated):
//   [0 .. 262144)        z_q_out [B,C,H,W]
//   [262144]             loss (scalar)
//   [262145 .. 270337)   token_ids [B,H,W] as float
//   [270337 .. 532481)   new_embedding [K,C]
//   [532481 .. 540673)   new_cluster_sizes [K]

#define NTOK   8192
#define NCODE  8192
#define CDIM   32
#define HW     256
#define DECAYF 0.99f
#define EPSF   0.01f

#define OUT_ZQ   0
#define OUT_LOSS 262144
#define OUT_IDS  262145
#define OUT_EMB  270337
#define OUT_CS   532481

// workspace byte offsets
#define WS_ZN     0u        // zn  row-major [N,C] f32      = 1048576 B
#define WS_ZNT    1048576u  // znT chan-major [C,N] f32     = 1048576 B
#define WS_PMAX   2097152u  // pmax [32 chunks][8192] f32   = 1048576 B
#define WS_PACK   3145728u  // 8192 u64                     = 65536 B  <- zeroed
#define WS_BINS   3211264u  // 8192 i32                     = 32768 B
#define WS_LOSS   3244032u  // 1 f32
#define WS_ZEND   3244036u
#define WS_ZERO_BYTES (WS_ZEND - WS_PACK)
#define WS_IDS    3244036u  // 8192 i32
#define WS_POS    3276804u  // 8192 i32
#define WS_OFFS   3309572u  // 8192 i32
#define WS_SORTED 3342340u  // 8192 i32  (end 3375108; R4 proved ws >= 5.3 MB)

#define CHUNK  256          // codes per block in k_max/k_pick
#define NCHUNK (NCODE / CHUNK)
#define TILES  (CHUNK / 16)

typedef __attribute__((ext_vector_type(8))) short bf16x8;
typedef __attribute__((ext_vector_type(4))) float f32x4;

__device__ inline unsigned short f2bf(float x) {
    unsigned u = __float_as_uint(x);
    return (unsigned short)((u + 0x7FFFu + ((u >> 16) & 1u)) >> 16);
}
__device__ inline unsigned fmap(float s) {   // monotonic f32 -> u32
    unsigned u = __float_as_uint(s);
    return (u & 0x80000000u) ? ~u : (u | 0x80000000u);
}

// -------- Kernel A: transpose + L2 normalize; write zn (row) + znT (chan) ------
__global__ __launch_bounds__(256) void k_prep(const float* __restrict__ z,
                                              float* __restrict__ zn,
                                              float* __restrict__ znT) {
    int n = blockIdx.x * 256 + threadIdx.x;       // token = b*256 + hw
    int b = n >> 8, hw = n & 255;
    const float* zp = z + (size_t)b * (CDIM * HW) + hw;
    float v[CDIM];
    float ss = 0.f;
#pragma unroll
    for (int c = 0; c < CDIM; ++c) {
        float t = zp[c * HW];
        v[c] = t;
        ss += t * t;
    }
    float d = fmaxf(sqrtf(ss), 1e-12f);
    float* o = zn + (size_t)n * CDIM;
#pragma unroll
    for (int c = 0; c < CDIM; ++c) {
        float t = v[c] / d;
        o[c] = t;
        znT[(size_t)c * NTOK + n] = t;            // coalesced per c
    }
}

// helper: stage one emb chunk (CHUNK x 32 fp32) as bf16 into LDS, row-major
__device__ inline void stage_emb_bf16(const float* __restrict__ emb, int kbase,
                                      unsigned short* lbs) {
    const float4* src = (const float4*)(emb + (size_t)kbase * CDIM);
    ushort4* dst = (ushort4*)lbs;
#pragma unroll
    for (int i = 0; i < 8; ++i) {
        int j = threadIdx.x + i * 256;
        float4 v = src[j];
        ushort4 h;
        h.x = f2bf(v.x); h.y = f2bf(v.y); h.z = f2bf(v.z); h.w = f2bf(v.w);
        dst[j] = h;
    }
}

// helper: load 4 A-frags (64 tokens) from fp32 zn, converting to bf16
__device__ inline void load_afrags(const float* __restrict__ zn, int wtok,
                                   int col, int quad, bf16x8* a) {
#pragma unroll
    for (int f = 0; f < 4; ++f) {
        const float4* zp =
            (const float4*)(zn + (size_t)(wtok + f * 16 + col) * CDIM + quad * 8);
        float4 x = zp[0], y = zp[1];
        bf16x8 v;
        v[0] = (short)f2bf(x.x); v[1] = (short)f2bf(x.y);
        v[2] = (short)f2bf(x.z); v[3] = (short)f2bf(x.w);
        v[4] = (short)f2bf(y.x); v[5] = (short)f2bf(y.y);
        v[6] = (short)f2bf(y.z); v[7] = (short)f2bf(y.w);
        a[f] = v;
    }
}

// -------- Kernel B1: MFMA scan -> pmax[chunk][tok] partial max (no atomics) ----
__global__ __launch_bounds__(256) void k_max(const float* __restrict__ zn,
                                             const float* __restrict__ emb,
                                             float* __restrict__ pmax) {
    __shared__ unsigned short lbs[CHUNK * CDIM];  // 16 KiB
    __shared__ float lmax[256];
    int kbase = blockIdx.y * CHUNK;
    stage_emb_bf16(emb, kbase, lbs);
    __syncthreads();

    int wave = threadIdx.x >> 6, lane = threadIdx.x & 63;
    int col = lane & 15, quad = lane >> 4;
    int wtok = blockIdx.x * 256 + wave * 64;

    bf16x8 a[4];
    load_afrags(zn, wtok, col, quad, a);

    const bf16x8* bl = (const bf16x8*)lbs;
    const f32x4 zero4 = {0.f, 0.f, 0.f, 0.f};
    float m[4][4];
#pragma unroll
    for (int f = 0; f < 4; ++f)
#pragma unroll
        for (int r = 0; r < 4; ++r) m[f][r] = -1e30f;

    for (int t = 0; t < TILES; ++t) {
        bf16x8 b = bl[(t * 16 + col) * 4 + quad];
#pragma unroll
        for (int f = 0; f < 4; ++f) {
            f32x4 d = __builtin_amdgcn_mfma_f32_16x16x32_bf16(a[f], b, zero4, 0, 0, 0);
#pragma unroll
            for (int r = 0; r < 4; ++r) m[f][r] = fmaxf(m[f][r], d[r]);
        }
    }
    // reduce over 16 code-columns (xor lane bits 0..3), park in LDS, store row
#pragma unroll
    for (int f = 0; f < 4; ++f)
#pragma unroll
        for (int r = 0; r < 4; ++r) {
            float v = m[f][r];
#pragma unroll
            for (int s = 1; s < 16; s <<= 1) v = fmaxf(v, __shfl_xor(v, s));
            if (col == 0) lmax[wave * 64 + f * 16 + quad * 4 + r] = v;
        }
    __syncthreads();
    pmax[(size_t)blockIdx.y * NTOK + blockIdx.x * 256 + threadIdx.x] =
        lmax[threadIdx.x];
}

// -------- Kernel B2: reduce partials -> threshold; rescan; exact fp32 rescore ---
__global__ __launch_bounds__(256) void k_pick(const float* __restrict__ zn,
                                              const float* __restrict__ emb,
                                              const float* __restrict__ pmax,
                                              unsigned long long* __restrict__ packed) {
    __shared__ unsigned short lbs[CHUNK * CDIM];  // 16 KiB
    __shared__ float lthr[256];
    int kbase = blockIdx.y * CHUNK;
    stage_emb_bf16(emb, kbase, lbs);
    {
        int tok = blockIdx.x * 256 + threadIdx.x;
        float mx = -1e30f;
#pragma unroll
        for (int ch = 0; ch < NCHUNK; ++ch)       // 32 coalesced loads
            mx = fmaxf(mx, pmax[(size_t)ch * NTOK + tok]);
        lthr[threadIdx.x] = mx - EPSF;
    }
    __syncthreads();

    int wave = threadIdx.x >> 6, lane = threadIdx.x & 63;
    int col = lane & 15, quad = lane >> 4;
    int wtok = blockIdx.x * 256 + wave * 64;

    bf16x8 a[4];
    load_afrags(zn, wtok, col, quad, a);

    float thr[4][4];
#pragma unroll
    for (int f = 0; f < 4; ++f)
#pragma unroll
        for (int r = 0; r < 4; ++r)
            thr[f][r] = lthr[wave * 64 + f * 16 + quad * 4 + r];

    const bf16x8* bl = (const bf16x8*)lbs;
    const f32x4 zero4 = {0.f, 0.f, 0.f, 0.f};

    for (int t = 0; t < TILES; ++t) {
        bf16x8 b = bl[(t * 16 + col) * 4 + quad];
#pragma unroll
        for (int f = 0; f < 4; ++f) {
            f32x4 d = __builtin_amdgcn_mfma_f32_16x16x32_bf16(a[f], b, zero4, 0, 0, 0);
#pragma unroll
            for (int r = 0; r < 4; ++r) {
                if (d[r] >= thr[f][r]) {          // rare: ~1.1 per token total
                    int tok = wtok + f * 16 + quad * 4 + r;
                    int code = kbase + t * 16 + col;
                    const float* zp = zn + (size_t)tok * CDIM;
                    const float* ep = emb + (size_t)code * CDIM;
                    float a0 = 0.f, a1 = 0.f, a2 = 0.f, a3 = 0.f;
#pragma unroll
                    for (int j = 0; j < 8; ++j) {
                        a0 = __builtin_fmaf(zp[4 * j + 0], ep[4 * j + 0], a0);
                        a1 = __builtin_fmaf(zp[4 * j + 1], ep[4 * j + 1], a1);
                        a2 = __builtin_fmaf(zp[4 * j + 2], ep[4 * j + 2], a2);
                        a3 = __builtin_fmaf(zp[4 * j + 3], ep[4 * j + 3], a3);
                    }
                    float s = (a0 + a1) + (a2 + a3);
                    atomicMax(packed + tok, ((unsigned long long)fmap(s) << 13) |
                                            (unsigned long long)(8191 - code));
                }
            }
        }
    }
}

// -------- Kernel C: blocks 0..1023 = z_q gather + loss; 1024..1055 = ids/pos ----
__global__ __launch_bounds__(256) void k_postzq(const unsigned long long* __restrict__ packed,
                                                const float* __restrict__ znT,
                                                const float* __restrict__ emb,
                                                int* __restrict__ bins,
                                                int* __restrict__ ids,
                                                int* __restrict__ pos,
                                                float* __restrict__ out,
                                                float* __restrict__ loss_acc) {
    if (blockIdx.x >= 1024) {                     // post: token per thread
        int n = (blockIdx.x - 1024) * 256 + threadIdx.x;
        int id = 8191 - (int)(packed[n] & 8191ull);
        ids[n] = id;
        out[OUT_IDS + n] = (float)id;
        pos[n] = atomicAdd(bins + id, 1);         // 8192 scattered atomics total
        return;
    }
    __shared__ float lsum[4];
    int b = blockIdx.x >> 5, c = blockIdx.x & 31;
    int hw = threadIdx.x;
    int n = b * 256 + hw;
    int id = 8191 - (int)(packed[n] & 8191ull);
    float ev = emb[(size_t)id * CDIM + c];        // true gather (L2)
    float zv = znT[(size_t)c * NTOK + n];         // coalesced
    out[OUT_ZQ + ((size_t)b * CDIM + c) * HW + hw] = ev;  // coalesced
    float dd = ev - zv;
    float s = dd * dd;
#pragma unroll
    for (int off = 32; off > 0; off >>= 1) s += __shfl_down(s, off);
    if ((hw & 63) == 0) lsum[hw >> 6] = s;
    __syncthreads();
    if (hw == 0)
        atomicAdd(loss_acc, lsum[0] + lsum[1] + lsum[2] + lsum[3]);  // 1/block
}

// -------- Kernel S: single-block exclusive scan of bins + place sorted ---------
__global__ __launch_bounds__(1024) void k_scanplace(const int* __restrict__ bins,
                                                    const int* __restrict__ ids,
                                                    const int* __restrict__ pos,
                                                    int* __restrict__ offs,
                                                    int* __restrict__ sorted) {
    __shared__ int sc[2][1024];
    int t = threadIdx.x;
    int loc[8];
    int s = 0;
#pragma unroll
    for (int i = 0; i < 8; ++i) {                 // local exclusive prefix
        loc[i] = s;
        s += bins[t * 8 + i];
    }
    sc[0][t] = s;
    __syncthreads();
    int src = 0;
    for (int d = 1; d < 1024; d <<= 1) {          // Hillis-Steele inclusive
        sc[1 - src][t] = sc[src][t] + (t >= d ? sc[src][t - d] : 0);
        src ^= 1;
        __syncthreads();
    }
    int excl = sc[src][t] - s;                    // exclusive block prefix
#pragma unroll
    for (int i = 0; i < 8; ++i) offs[t * 8 + i] = excl + loc[i];
    __syncthreads();
    for (int n = t; n < NTOK; n += 1024)
        sorted[offs[ids[n]] + pos[n]] = n;
}

// -------- Kernel E: EMA update via segment gather + renormalize ---------------
__global__ __launch_bounds__(256) void k_update(const float* __restrict__ zn,
                                                const float* __restrict__ emb,
                                                const float* __restrict__ cs,
                                                const int* __restrict__ bins,
                                                const int* __restrict__ offs,
                                                const int* __restrict__ sorted,
                                                const float* __restrict__ loss_acc,
                                                float* __restrict__ out) {
    int idx = blockIdx.x * 256 + threadIdx.x;
    int k = idx >> 5, c = idx & 31;
    int bi = bins[k];
    int off = offs[k];
    float t = 0.f;
    for (int i = 0; i < bi; ++i) {                // avg 1 iter; broadcast index
        int n = sorted[off + i];
        t += zn[(size_t)n * CDIM + c];            // coalesced 128B row
    }
    float bf = (float)bi;
    bool zero = (bi == 0);
    t /= (zero ? 1.0f : bf);
    float ss = t * t;
#pragma unroll
    for (int s = 1; s < 32; s <<= 1) ss += __shfl_xor(ss, s);
    float d = fmaxf(sqrtf(ss), 1e-12f);
    float ew = emb[idx];
    float en = zero ? ew : (t / d);
    float w = ew * DECAYF + (1.0f - DECAYF) * en;
    float ss2 = w * w;
#pragma unroll
    for (int s = 1; s < 32; s <<= 1) ss2 += __shfl_xor(ss2, s);
    float d2 = fmaxf(sqrtf(ss2), 1e-12f);
    out[OUT_EMB + idx] = w / d2;
    if (c == 0) out[OUT_CS + k] = cs[k] * DECAYF + (1.0f - DECAYF) * bf;
    if (idx == 0) out[OUT_LOSS] = loss_acc[0] * (1.0f / 262144.0f);
}

extern "C" void kernel_launch(void* const* d_in, const int* in_sizes, int n_in,
                              void* d_out, int out_size, void* d_ws, size_t ws_size,
                              hipStream_t stream) {
    const float* z   = (const float*)d_in[0];   // [32,32,16,16]
    const float* emb = (const float*)d_in[1];   // [8192,32]
    const float* cs  = (const float*)d_in[2];   // [8192]
    float* out = (float*)d_out;
    char* ws = (char*)d_ws;

    float* zn                  = (float*)(ws + WS_ZN);
    float* znT                 = (float*)(ws + WS_ZNT);
    float* pmax                = (float*)(ws + WS_PMAX);
    unsigned long long* packed = (unsigned long long*)(ws + WS_PACK);
    int* bins                  = (int*)(ws + WS_BINS);
    float* loss_acc            = (float*)(ws + WS_LOSS);
    int* ids                   = (int*)(ws + WS_IDS);
    int* pos                   = (int*)(ws + WS_POS);
    int* offs                  = (int*)(ws + WS_OFFS);
    int* sorted                = (int*)(ws + WS_SORTED);

    hipMemsetAsync(ws + WS_PACK, 0, WS_ZERO_BYTES, stream);

    k_prep<<<dim3(NTOK / 256), 256, 0, stream>>>(z, zn, znT);
    k_max<<<dim3(NTOK / 256, NCHUNK), 256, 0, stream>>>(zn, emb, pmax);
    k_pick<<<dim3(NTOK / 256, NCHUNK), 256, 0, stream>>>(zn, emb, pmax, packed);
    k_postzq<<<dim3(1056), 256, 0, stream>>>(packed, znT, emb, bins, ids, pos, out, loss_acc);
    k_scanplace<<<dim3(1), 1024, 0, stream>>>(bins, ids, pos, offs, sorted);
    k_update<<<dim3(1024), 256, 0, stream>>>(zn, emb, cs, bins, offs, sorted, loss_acc, out);
}